// Round 10
// baseline (109.211 us; speedup 1.0000x reference)
//
#include <hip/hip_runtime.h>
#include <math.h>

// Problem constants
#define DIM   256
#define NST   256
#define LSEQ  512
#define BAT   2
#define DTSZ  64
#define PCOLS 576
#define NROWS 1024

typedef float    f32x4 __attribute__((ext_vector_type(4)));
typedef unsigned u32x4 __attribute__((ext_vector_type(4)));

constexpr float LOG2E = 1.4426950408889634f;

__device__ __forceinline__ float fexp2(float v) {
#if __has_builtin(__builtin_amdgcn_exp2f)
    return __builtin_amdgcn_exp2f(v);
#else
    return exp2f(v);
#endif
}

__device__ __forceinline__ float softplusf(float v) {
    return (v > 20.f) ? v : log1pf(__expf(v));
}

// LDS-only barrier: waits lgkmcnt(0) but leaves global (vmcnt) loads in flight.
__device__ __forceinline__ void barrier_lds_only() {
    __builtin_amdgcn_s_waitcnt(0xC07F);   // vmcnt=63, expcnt=7, lgkmcnt=0
    __builtin_amdgcn_s_barrier();
}

// fp32 -> bf16 (RNE) as u16.
__device__ __forceinline__ unsigned short rne16(float f) {
    unsigned u = __float_as_uint(f);
    return (unsigned short)((u + 0x7fffu + ((u >> 16) & 1u)) >> 16);
}

// v_cvt_pk_bf16_f32: two fp32 -> packed bf16x2 (lo = src0, hi = src1), 1 instr.
// (harness-verified R4)
__device__ __forceinline__ unsigned cvtpk(float lo, float hi) {
    unsigned r;
    asm("v_cvt_pk_bf16_f32 %0, %1, %2" : "=v"(r) : "v"(lo), "v"(hi));
    return r;
}

// MFMA via inline asm. D = A(16x32 bf16) * B(32x16 bf16) + C.
// A: row=lane&15, k=(lane>>4)*8+i.  B: col=lane&15, k=(lane>>4)*8+i.
// C/D: col=lane&15, row=(lane>>4)*4+r.   (harness-verified R4)
__device__ __forceinline__ f32x4 mfma16(u32x4 a, u32x4 b, f32x4 c) {
    asm("v_mfma_f32_16x16x32_bf16 %0, %1, %2, %0" : "+v"(c) : "v"(a), "v"(b));
    return c;
}

// ---------------- proj_mfma: x@W_in via bf16 MFMA (R4-verified core, R8
// float2 stage). This round: beta/gamma stored as SEPARATE f32 quad-streams
// (two f32x4 stores per lane; pack_bg deleted) so the scan consumes them
// with zero decode VALU. Layout: beta4[(row>>2)*NST + n][r] = beta(row,n),
// r = row & 3; same for gam4. acc1[r]/acc2[r] are rows rowbase..+3 (R4 C/D
// mapping), rowbase % 4 == 0 -> one aligned 16B store each.
__global__ __launch_bounds__(256, 2) void proj_mfma(
    const float* __restrict__ x, const float* __restrict__ W_in,
    float* __restrict__ beta4,         // [NROWS/4][NST][4] f32
    float* __restrict__ gam4,          // [NROWS/4][NST][4] f32
    float* __restrict__ draw)          // [NROWS, DTSZ] fp32 dt_raw
{
    __shared__ unsigned short Bt[64][264];   // 33792 B
    const int tid  = threadIdx.x;
    const int lane = tid & 63;
    const int mt   = blockIdx.x / 9;
    const int role = blockIdx.x % 9;

    const int base0 = (role < 8) ? (64  + 32 * role) : 0;
    const int base1 = (role < 8) ? (320 + 32 * role) : 32;
    {
        const int cs = tid & 15;          // col-pair index (0..15)
        const int kq = tid >> 4;          // 0..15
        #pragma unroll 8
        for (int p = 0; p < 16; ++p) {
            const int k = p * 16 + kq;
            const float2 v0 = *(const float2*)&W_in[k * PCOLS + base0 + 2 * cs];
            const float2 v1 = *(const float2*)&W_in[k * PCOLS + base1 + 2 * cs];
            Bt[2 * cs][k]          = rne16(v0.x);
            Bt[2 * cs + 1][k]      = rne16(v0.y);
            Bt[32 + 2 * cs][k]     = rne16(v1.x);
            Bt[32 + 2 * cs + 1][k] = rne16(v1.y);
        }
    }
    __syncthreads();

    const int w    = tid >> 6;
    const int wm   = w >> 1, wn = w & 1;
    const int row  = mt * 32 + wm * 16 + (lane & 15);
    const int koff = (lane >> 4) * 8;
    const float* xp = x + row * DIM + koff;
    const unsigned short* bp1 = &Bt[16 * wn + (lane & 15)][koff];
    const unsigned short* bp2 = &Bt[32 + 16 * wn + (lane & 15)][koff];

    f32x4 acc1 = {0.f, 0.f, 0.f, 0.f};
    f32x4 acc2 = {0.f, 0.f, 0.f, 0.f};
    #pragma unroll
    for (int kk = 0; kk < 8; ++kk) {     // K = 8 x 32
        const float4 xa = *(const float4*)(xp + kk * 32);
        const float4 xb = *(const float4*)(xp + kk * 32 + 4);
        u32x4 a;
        a.x = cvtpk(xa.x, xa.y);
        a.y = cvtpk(xa.z, xa.w);
        a.z = cvtpk(xb.x, xb.y);
        a.w = cvtpk(xb.z, xb.w);
        const u32x4 b1 = *(const u32x4*)(bp1 + kk * 32);
        const u32x4 b2 = *(const u32x4*)(bp2 + kk * 32);
        acc1 = mfma16(a, b1, acc1);
        acc2 = mfma16(a, b2, acc2);
    }

    const int rowbase = mt * 32 + wm * 16 + (lane >> 4) * 4;   // %4 == 0
    if (role < 8) {
        const int n = 32 * role + 16 * wn + (lane & 15);
        const int q = (rowbase >> 2) * NST + n;
        *(f32x4*)&beta4[q * 4] = acc1;       // rows rowbase..+3, state n
        *(f32x4*)&gam4 [q * 4] = acc2;
    } else {
        const int c1 = 16 * wn + (lane & 15);
        #pragma unroll
        for (int r = 0; r < 4; ++r) {
            draw[(rowbase + r) * DTSZ + c1]      = acc1[r];
            draw[(rowbase + r) * DTSZ + 32 + c1] = acc2[r];
        }
    }
}

// ---------------- scan1p: R8 skeleton (passing, 40.7us), with beta/gamma
// consumed as separate f32 quad-streams: the 2 decode VALU ops per step
// (shl, and) are gone — per-step body is now mul,exp,mul,fma,mul + ds_write
// (6 VALU, was 8; ~-1024 VALU/thread). Loads: 4 dwordx4/window (was 2) —
// scan measured at 2.9% HBM peak, bytes are free. Barriers/reduce identical.
__global__ __launch_bounds__(256, 2) void scan1p(
    const float* __restrict__ x,            // [NROWS, DIM]
    const float* __restrict__ alpha_log,    // [DIM, NST]
    const float* __restrict__ delta,        // [DIM]
    const float* __restrict__ beta4,        // [NROWS/4][NST][4]
    const float* __restrict__ gam4,         // [NROWS/4][NST][4]
    const float* __restrict__ draw,         // [NROWS, DTSZ]
    const float* __restrict__ W_dt,         // [DTSZ, DIM]
    const float* __restrict__ b_dt,         // [DIM]
    float* __restrict__ out)                // [NROWS, DIM]
{
    __shared__ float part[2][32][NST];      // 64 KB double-buffered (R8 scheme)
    __shared__ float dts[LSEQ], dxs[LSEQ], xcol[LSEQ];   // 3 x 2 KB
    __shared__ float wdt[DTSZ];             // 256 B
    const int n = threadIdx.x;
    // XCD swizzle (R10-verified): XCDs 0-3 -> b=0, 4-7 -> b=1.
    const int xcd  = blockIdx.x & 7;
    const int slot = blockIdx.x >> 3;       // 0..63
    const int b = xcd >> 2;
    const int d = slot * 4 + (xcd & 3);
    const int rb  = b * LSEQ;
    const int rbq = rb >> 2;                // quad-row base (= b*128)

    if (n < DTSZ) wdt[n] = W_dt[n * DIM + d];
    #pragma unroll
    for (int it = 0; it < 2; ++it) {
        const int l = n + it * 256;
        xcol[l] = x[(rb + l) * DIM + d];
    }
    const float aln = -__expf(alpha_log[d * NST + n]) * LOG2E;
    const float dv  = delta[d];
    const float bdv = b_dt[d];

    // 6-window beta/gamma prefetch (24 dwordx4 loads), in flight through the
    // dt prologue.
    f32x4 bgB[8][2], bgG[8][2];             // 8-slot rotation of row-quads
    #pragma unroll
    for (int pw = 0; pw < 6; ++pw) {
        #pragma unroll
        for (int h = 0; h < 2; ++h) {
            const int q = (rbq + pw * 2 + h) * NST + n;
            bgB[pw][h] = *(const f32x4*)&beta4[q * 4];
            bgG[pw][h] = *(const f32x4*)&gam4 [q * 4];
        }
    }

    barrier_lds_only();                     // wdt/xcol visible; vmcnt untouched

    // Fused dt GEMM: dts[l] = softplus(draw[rb+l,:] . wdt + b_dt[d])
    #pragma unroll
    for (int it = 0; it < 2; ++it) {
        const int l = n + it * 256;
        const float4* dr = (const float4*)&draw[(rb + l) * DTSZ];
        float acc = bdv;
        #pragma unroll
        for (int c = 0; c < 16; ++c) {
            const float4 v  = dr[c];
            const float4 wv = *(const float4*)&wdt[c * 4];
            acc = fmaf(v.x, wv.x, acc);
            acc = fmaf(v.y, wv.y, acc);
            acc = fmaf(v.z, wv.z, acc);
            acc = fmaf(v.w, wv.w, acc);
        }
        const float sp = softplusf(acc);
        dts[l] = sp;
        dxs[l] = sp * xcol[l];
    }
    __syncthreads();                        // dts/dxs ready

    float s = 0.f;
    #pragma unroll 8
    for (int w = 0; w < 64; ++w) {
        const int cur = w & 7;              // static under unroll-8
        const int pf  = (w + 6) & 7;
        const int bufsel = (w >> 2) & 1;    // static: group double-buffer
        if (w + 6 < 64) {                   // issue window w+6 while computing w
            #pragma unroll
            for (int h = 0; h < 2; ++h) {
                const int q = (rbq + (w + 6) * 2 + h) * NST + n;
                bgB[pf][h] = *(const f32x4*)&beta4[q * 4];
                bgG[pf][h] = *(const f32x4*)&gam4 [q * 4];
            }
        }
        float4 dta = *(const float4*)&dts[w * 8];
        float4 dtb = *(const float4*)&dts[w * 8 + 4];
        float4 dxa = *(const float4*)&dxs[w * 8];
        float4 dxb = *(const float4*)&dxs[w * 8 + 4];
        const float dtw[8] = {dta.x, dta.y, dta.z, dta.w, dtb.x, dtb.y, dtb.z, dtb.w};
        const float dxw[8] = {dxa.x, dxa.y, dxa.z, dxa.w, dxb.x, dxb.y, dxb.z, dxb.w};

        const int prow = (w & 3) * 8;
        #pragma unroll
        for (int t = 0; t < 8; ++t) {       // static t: quads const-indexed
            const float be = bgB[cur][t >> 2][t & 3];
            const float ga = bgG[cur][t >> 2][t & 3];
            float a = fexp2(dtw[t] * aln);
            s = fmaf(a, s, dxw[t] * be);
            part[bufsel][prow + t][n] = s * ga;   // 2-way bank alias: free
        }

        if ((w & 3) == 3) {                 // every 32 steps: reduce 32 rows x 256
            barrier_lds_only();             // writes complete; WAR fence for g+2
            const int trow = n >> 3, seg = n & 7;
            float sum = 0.f;
            #pragma unroll
            for (int k = 0; k < 32; ++k)
                sum += part[bufsel][trow][seg * 32 + ((k + n) & 31)];  // 0-conflict
            sum += __shfl_xor(sum, 1);
            sum += __shfl_xor(sum, 2);
            sum += __shfl_xor(sum, 4);
            if (seg == 0) {
                const int l = (w >> 2) * 32 + trow;
                out[(rb + l) * DIM + d] = sum + xcol[l] * dv;
            }
            // no trailing barrier: next group writes the OTHER buffer
        }
    }
}

extern "C" void kernel_launch(void* const* d_in, const int* in_sizes, int n_in,
                              void* d_out, int out_size, void* d_ws, size_t ws_size,
                              hipStream_t stream) {
    const float* x         = (const float*)d_in[0];
    const float* W_in      = (const float*)d_in[1];
    const float* W_dt      = (const float*)d_in[2];
    const float* b_dt      = (const float*)d_in[3];
    const float* alpha_log = (const float*)d_in[4];
    const float* delta     = (const float*)d_in[5];
    float* out = (float*)d_out;

    // Workspace: beta4 1MB | gam4 1MB | draw 256KB
    float* beta4 = (float*)d_ws;
    float* gam4  = beta4 + NROWS * NST;
    float* draw  = gam4  + NROWS * NST;

    proj_mfma<<<32 * 9, 256, 0, stream>>>(x, W_in, beta4, gam4, draw);
    scan1p<<<BAT * DIM, 256, 0, stream>>>(x, alpha_log, delta, beta4, gam4,
                                          draw, W_dt, b_dt, out);
}